// Round 4
// baseline (519.016 us; speedup 1.0000x reference)
//
#include <hip/hip_runtime.h>
#include <hip/hip_bf16.h>

// Problem constants (B=2, L=2048, Dm=768, di=1536, ds=16, dc=4)
#define BB 2
#define LL 2048
#define DM 768
#define DI 1536
#define DS 16
#define MM (BB*LL)   // 4096 rows
#define NCH 32       // scan chunks
#define CHL 64       // steps per chunk
#define SEQS (BB*DI*DS)  // 49152 independent scalar recurrences
#define NC2 1664     // delta GEMM fused N: 1536 (W_dt) + 32 (W_x) + 96 pad = 13*128

typedef __hip_bfloat16 bf16;
typedef short bf16x8 __attribute__((ext_vector_type(8)));
typedef float f32x4  __attribute__((ext_vector_type(4)));

// CK-style barrier: drains LDS ops only, leaves global loads in flight
// (plain __syncthreads() emits s_waitcnt vmcnt(0) which kills the pipeline).
__device__ __forceinline__ void sync_lds() {
  asm volatile("s_waitcnt lgkmcnt(0)\n\ts_barrier" ::: "memory");
}

// ---------------- fp32 -> bf16 convert (4 elems/thread) ----------------
struct bf4 { __hip_bfloat16 a, b, c, d; };
__global__ void cvt4_k(const float* __restrict__ in, __hip_bfloat16* __restrict__ out, int n4) {
  int i = blockIdx.x * 256 + threadIdx.x;
  if (i < n4) {
    float4 v = ((const float4*)in)[i];
    bf4 o = { __float2bfloat16(v.x), __float2bfloat16(v.y),
              __float2bfloat16(v.z), __float2bfloat16(v.w) };
    ((bf4*)out)[i] = o;
  }
}

// ---------------- build Wcomb[1664][1536] bf16 = [W_dt ; W_x ; 0-pad] ----------------
__global__ void wcomb_k(const float* __restrict__ Wdt, const float* __restrict__ Wx,
                        __hip_bfloat16* __restrict__ out) {
  int i = blockIdx.x * 256 + threadIdx.x;          // one float4 per thread
  if (i >= NC2 * DI / 4) return;
  int e = i * 4;
  int row = e / DI, colb = e % DI;
  float4 v;
  if (row < DI)            v = ((const float4*)Wdt)[i];
  else if (row < DI + 32)  v = *(const float4*)(Wx + (size_t)(row - DI) * DI + colb);
  else                     v = make_float4(0.f, 0.f, 0.f, 0.f);
  bf4 o = { __float2bfloat16(v.x), __float2bfloat16(v.y),
            __float2bfloat16(v.z), __float2bfloat16(v.w) };
  ((bf4*)out)[i] = o;
}

// ---------------- pipelined NT bf16 MFMA GEMM, BMx128 tile ----------------
// C[M,N] = A[M,K] * W[N,K]^T.  256 threads = 4 waves (2x2), wave tile (BM/2)x64.
// K-loop: buffer_load->regs prefetch (tile k+1) || MFMA (tile k), double-buffered
// LDS, ONE lgkm-only barrier per iter. Global loads stay in flight across it.
// EPI: 0 = plain fp32 store (stride N)
//      2 = split: col<DI -> C (stride DI), else -> C2 (stride DI)   [xz GEMM]
//      3 = col<DI -> softplus(v+bias[col]) -> C (stride DI);
//          col in [DI,DI+32) -> C2 (stride 32); else discard        [delta+xdbl]
template<int EPI, int BM>
__global__ __launch_bounds__(256) void gemm_pipe(const bf16* __restrict__ A,
                                                 const bf16* __restrict__ W,
                                                 float* __restrict__ C,
                                                 float* __restrict__ C2,
                                                 const float* __restrict__ bias,
                                                 int M, int N, int K) {
  constexpr int ABLK = BM / 16;     // 16-row blocks in A tile
  constexpr int NA   = BM / 64;     // 16B chunks per thread for A (128->2, 64->1)
  __shared__ short sA[2][BM * 32];  // frag-major: [rb][lane] 16B units
  __shared__ short sB[2][128 * 32];
  const int t = threadIdx.x;
  const int m0 = blockIdx.y * BM, n0 = blockIdx.x * 128;
  const int w = t >> 6, lane = t & 63;
  const int wm = (w >> 1) * (BM / 2), wn = (w & 1) * 64;
  const int ga = wm >> 4, gb = wn >> 4;

  f32x4 acc[BM / 32][4] = {};

  // staging chunk descriptors (chunk s: lane l = s&63, row-block rb)
  int aoff[NA]; const bf16* gap[NA];
  #pragma unroll
  for (int j = 0; j < NA; j++) {
    int s = t + j * 256;
    int l = s & 63, rb = (s >> 6) % ABLK;
    aoff[j] = s * 8;
    gap[j] = A + (size_t)(m0 + rb * 16 + (l & 15)) * K + (l >> 4) * 8;
  }
  int boff[2]; const bf16* gbp[2];
  #pragma unroll
  for (int j = 0; j < 2; j++) {
    int s = t + j * 256;
    int l = s & 63, rb = s >> 6;
    boff[j] = s * 8;
    gbp[j] = W + (size_t)(n0 + rb * 16 + (l & 15)) * K + (l >> 4) * 8;
  }

  float4 pa[NA], pb[2];
  #pragma unroll
  for (int j = 0; j < NA; j++) pa[j] = *(const float4*)gap[j];
  #pragma unroll
  for (int j = 0; j < 2; j++)  pb[j] = *(const float4*)gbp[j];

  int p = 0;
  for (int k0 = 0; k0 < K; k0 += 32) {
    // write current tile to LDS buffer p (vmcnt wait covers only our own
    // loads, issued one full MFMA-phase ago)
    #pragma unroll
    for (int j = 0; j < NA; j++) *(float4*)(&sA[p][aoff[j]]) = pa[j];
    #pragma unroll
    for (int j = 0; j < 2; j++)  *(float4*)(&sB[p][boff[j]]) = pb[j];
    // issue next tile's global loads (in flight across barrier + MFMA)
    if (k0 + 32 < K) {
      #pragma unroll
      for (int j = 0; j < NA; j++) { gap[j] += 32; pa[j] = *(const float4*)gap[j]; }
      #pragma unroll
      for (int j = 0; j < 2; j++)  { gbp[j] += 32; pb[j] = *(const float4*)gbp[j]; }
    }
    sync_lds();   // lgkm-only: does NOT drain the prefetch loads
    const bf16x8* fA = (const bf16x8*)sA[p];
    const bf16x8* fB = (const bf16x8*)sB[p];
    bf16x8 af[BM / 32], bfr[4];
    #pragma unroll
    for (int i = 0; i < BM / 32; i++) af[i]  = fA[(ga + i) * 64 + lane];
    #pragma unroll
    for (int j = 0; j < 4; j++)       bfr[j] = fB[(gb + j) * 64 + lane];
    #pragma unroll
    for (int i = 0; i < BM / 32; i++)
      #pragma unroll
      for (int j = 0; j < 4; j++)
        acc[i][j] = __builtin_amdgcn_mfma_f32_16x16x32_bf16(af[i], bfr[j], acc[i][j], 0, 0, 0);
    p ^= 1;
    // NOTE: no second barrier: next iter writes the other LDS buffer; WAR on
    // this buffer is protected by this iter's sync (readers drained lgkm first).
  }

  const int q = lane >> 4, mm = lane & 15;
  #pragma unroll
  for (int i = 0; i < BM / 32; i++)
    #pragma unroll
    for (int j = 0; j < 4; j++) {
      int r0  = m0 + wm + i * 16 + q * 4;
      int col = n0 + wn + j * 16 + mm;
      #pragma unroll
      for (int r = 0; r < 4; r++) {
        float v = acc[i][j][r];
        if (EPI == 0) {
          C[(size_t)(r0 + r) * N + col] = v;
        } else if (EPI == 2) {
          if (col < DI) C [(size_t)(r0 + r) * DI + col]        = v;
          else          C2[(size_t)(r0 + r) * DI + (col - DI)] = v;
        } else {  // EPI == 3
          if (col < DI) {
            float vv = v + bias[col];
            vv = (vv > 15.f) ? vv : __logf(1.f + __expf(vv));
            C[(size_t)(r0 + r) * DI + col] = vv;
          } else if (col < DI + 32) {
            C2[(size_t)(r0 + r) * 32 + (col - DI)] = v;
          }
        }
      }
    }
}

// ---------------- depthwise causal conv (dc=4) + SiLU; writes fp32 + bf16 ----------------
__global__ __launch_bounds__(256) void conv_silu_k(const float* __restrict__ xpart,
                                                   const float* __restrict__ Wc,
                                                   float* __restrict__ xc,
                                                   __hip_bfloat16* __restrict__ xcbf) {
  int idx = blockIdx.x * 256 + threadIdx.x;
  if (idx >= MM * DI) return;
  int d = idx % DI;
  int r = idx / DI;
  int l = r & (LL - 1);
  float4 wv = ((const float4*)Wc)[d];  // W_conv[d, 0, 0..3]
  const float* xp = xpart + (size_t)r * DI + d;
  float acc = wv.w * xp[0];
  if (l >= 1) acc += wv.z * xp[-(ptrdiff_t)DI];
  if (l >= 2) acc += wv.y * xp[-(ptrdiff_t)(2 * DI)];
  if (l >= 3) acc += wv.x * xp[-(ptrdiff_t)(3 * DI)];
  float s = acc / (1.f + __expf(-acc));   // silu
  xc[idx] = s;
  xcbf[idx] = __float2bfloat16(s);
}

// ================= chunked selective scan =================
__global__ __launch_bounds__(64) void scan_part_k(const float* __restrict__ delta,
                                                  const float* __restrict__ xdbl,
                                                  const float* __restrict__ A_log,
                                                  float* __restrict__ prodA,
                                                  float* __restrict__ hend) {
  __shared__ float sBC[CHL * 32];
  const int t = threadIdx.x;
  const int dg = blockIdx.x % (DI / 64);
  const int chunk = (blockIdx.x / (DI / 64)) % NCH;
  const int b = blockIdx.x / ((DI / 64) * NCH);
  const int d = dg * 64 + t;

  float a[16];
  #pragma unroll
  for (int s = 0; s < 16; s++) a[s] = -__expf(A_log[s]);

  const float4* src = (const float4*)(xdbl + ((size_t)b * LL + chunk * CHL) * 32);
  #pragma unroll
  for (int k = 0; k < 8; k++) ((float4*)sBC)[t + k * 64] = src[t + k * 64];
  __syncthreads();

  float h[16], p[16];
  #pragma unroll
  for (int s = 0; s < 16; s++) { h[s] = 0.f; p[s] = 1.f; }

  const float* dptr = delta + ((size_t)b * LL + chunk * CHL) * DI + d;
  #pragma unroll 2
  for (int i = 0; i < CHL; i++) {
    float dlt = dptr[(size_t)i * DI];
    const float4* bc = (const float4*)(sBC + i * 32);
    float4 B0 = bc[0], B1 = bc[1], B2 = bc[2], B3 = bc[3];
    float Bv[16] = {B0.x,B0.y,B0.z,B0.w, B1.x,B1.y,B1.z,B1.w,
                    B2.x,B2.y,B2.z,B2.w, B3.x,B3.y,B3.z,B3.w};
    #pragma unroll
    for (int s = 0; s < 16; s++) {
      float dA = __expf(dlt * a[s]);
      h[s] = dA * h[s] + dlt * Bv[s];
      p[s] *= dA;
    }
  }
  size_t o = (size_t)chunk * SEQS + ((size_t)b * DI + d) * 16;
  #pragma unroll
  for (int s = 0; s < 16; s += 4) {
    ((float4*)(prodA + o))[s >> 2] = make_float4(p[s], p[s+1], p[s+2], p[s+3]);
    ((float4*)(hend  + o))[s >> 2] = make_float4(h[s], h[s+1], h[s+2], h[s+3]);
  }
}

__global__ __launch_bounds__(64) void scan_comb_k(const float* __restrict__ prodA,
                                                  const float* __restrict__ hend,
                                                  float* __restrict__ hstart) {
  int idx = blockIdx.x * 64 + threadIdx.x;   // 0 .. SEQS-1
  float run = 0.f;
  #pragma unroll
  for (int c = 0; c < NCH; c++) {
    size_t o = (size_t)c * SEQS + idx;
    hstart[o] = run;
    run = prodA[o] * run + hend[o];
  }
}

__global__ __launch_bounds__(64) void scan_fin_k(const float* __restrict__ delta,
                                                 const float* __restrict__ xdbl,
                                                 const float* __restrict__ A_log,
                                                 const float* __restrict__ Dp,
                                                 const float* __restrict__ xc,
                                                 const float* __restrict__ z,
                                                 const float* __restrict__ hstart,
                                                 __hip_bfloat16* __restrict__ ypbf) {
  __shared__ float sBC[CHL * 32];
  const int t = threadIdx.x;
  const int dg = blockIdx.x % (DI / 64);
  const int chunk = (blockIdx.x / (DI / 64)) % NCH;
  const int b = blockIdx.x / ((DI / 64) * NCH);
  const int d = dg * 64 + t;

  float a[16];
  #pragma unroll
  for (int s = 0; s < 16; s++) a[s] = -__expf(A_log[s]);

  const float4* src = (const float4*)(xdbl + ((size_t)b * LL + chunk * CHL) * 32);
  #pragma unroll
  for (int k = 0; k < 8; k++) ((float4*)sBC)[t + k * 64] = src[t + k * 64];
  __syncthreads();

  float h[16];
  size_t o = (size_t)chunk * SEQS + ((size_t)b * DI + d) * 16;
  #pragma unroll
  for (int s = 0; s < 16; s += 4) {
    float4 v = ((const float4*)(hstart + o))[s >> 2];
    h[s] = v.x; h[s+1] = v.y; h[s+2] = v.z; h[s+3] = v.w;
  }
  const float Dv = Dp[d];

  const size_t rbase = (size_t)b * LL + chunk * CHL;
  const float* dptr = delta + rbase * DI + d;
  const float* xcp  = xc    + rbase * DI + d;
  const float* zp   = z     + rbase * DI + d;
  __hip_bfloat16* yp = ypbf + rbase * DI + d;

  #pragma unroll 2
  for (int i = 0; i < CHL; i++) {
    float dlt = dptr[(size_t)i * DI];
    const float4* bc = (const float4*)(sBC + i * 32);
    float4 B0 = bc[0], B1 = bc[1], B2 = bc[2], B3 = bc[3];
    float4 C0 = bc[4], C1 = bc[5], C2 = bc[6], C3 = bc[7];
    float Bv[16] = {B0.x,B0.y,B0.z,B0.w, B1.x,B1.y,B1.z,B1.w,
                    B2.x,B2.y,B2.z,B2.w, B3.x,B3.y,B3.z,B3.w};
    float Cv[16] = {C0.x,C0.y,C0.z,C0.w, C1.x,C1.y,C1.z,C1.w,
                    C2.x,C2.y,C2.z,C2.w, C3.x,C3.y,C3.z,C3.w};
    float y = 0.f;
    #pragma unroll
    for (int s = 0; s < 16; s++) {
      float dA = __expf(dlt * a[s]);
      h[s] = dA * h[s] + dlt * Bv[s];
      y += h[s] * Cv[s];
    }
    float xcv = xcp[(size_t)i * DI];
    float zv  = zp [(size_t)i * DI];
    float val = (y + Dv * xcv) * (zv / (1.f + __expf(-zv)));
    yp[(size_t)i * DI] = __float2bfloat16(val);
  }
}

extern "C" void kernel_launch(void* const* d_in, const int* in_sizes, int n_in,
                              void* d_out, int out_size, void* d_ws, size_t ws_size,
                              hipStream_t stream) {
  const float* x      = (const float*)d_in[0];
  const float* W_in   = (const float*)d_in[1];
  const float* W_conv = (const float*)d_in[2];
  const float* W_x    = (const float*)d_in[3];
  const float* W_dt   = (const float*)d_in[4];
  const float* b_dt   = (const float*)d_in[5];
  const float* A_log  = (const float*)d_in[6];
  const float* Dp     = (const float*)d_in[7];
  const float* W_out  = (const float*)d_in[8];
  float* out = (float*)d_out;

  char* ws = (char*)d_ws;
  // workspace layout (bytes), total 144441344
  float*          xpart  = (float*)(ws + 0);                         // 25165824
  float*          z      = (float*)(ws + 25165824);                  // 25165824
  __hip_bfloat16* xbf    = (__hip_bfloat16*)(ws + 50331648);         // 6291456 (dead after GEMM1)
  __hip_bfloat16* Winbf  = (__hip_bfloat16*)(ws + 56623104);         // 4718592
  float*          xc     = (float*)(ws + 61341696);                  // 25165824
  __hip_bfloat16* xcbf   = (__hip_bfloat16*)(ws + 86507520);         // 12582912
  float*          delta  = (float*)(ws + 103809024);                 // 25165824
  float*          xdbl   = (float*)(ws + 128974848);                 // 524288
  __hip_bfloat16* ypbf   = (__hip_bfloat16*)(ws + 129499136);        // 12582912
  __hip_bfloat16* Woutbf = (__hip_bfloat16*)(ws + 142082048);        // 2359296
  // aliases of dead regions:
  float*          prodA  = (float*)(ws + 0);                         // xpart region (dead after conv)
  float*          hend   = (float*)(ws + 6291456);
  float*          hstart = (float*)(ws + 12582912);
  __hip_bfloat16* Wcomb  = (__hip_bfloat16*)(ws + 50331648);         // xbf region: 1664*1536*2 = 5111808

  // fp32 -> bf16 converts
  cvt4_k<<<(786432 + 255) / 256, 256, 0, stream>>>(x, xbf, 786432);
  cvt4_k<<<(589824 + 255) / 256, 256, 0, stream>>>(W_in, Winbf, 589824);
  cvt4_k<<<(294912 + 255) / 256, 256, 0, stream>>>(W_out, Woutbf, 294912);

  // xz = x @ W_in.T (4096 x 3072, K=768), split-stored into xpart | z
  {
    dim3 g(3072 / 128, 4096 / 128);   // 768 blocks
    gemm_pipe<2, 128><<<g, 256, 0, stream>>>(xbf, Winbf, xpart, z, nullptr, MM, 2 * DI, DM);
  }
  // xc = silu(causal_dwconv(xpart))
  conv_silu_k<<<(MM * DI + 255) / 256, 256, 0, stream>>>(xpart, W_conv, xc, xcbf);
  // Wcomb = [W_dt ; W_x ; 0] bf16 (aliases xbf, dead after GEMM1)
  wcomb_k<<<(NC2 * DI / 4 + 255) / 256, 256, 0, stream>>>(W_dt, W_x, Wcomb);
  // delta = softplus(xc @ W_dt.T + b_dt) AND xdbl = xc @ W_x.T, one GEMM (N=1664)
  {
    dim3 g(NC2 / 128, 4096 / 128);    // 416 blocks
    gemm_pipe<3, 128><<<g, 256, 0, stream>>>(xcbf, Wcomb, delta, xdbl, b_dt, MM, NC2, DI);
  }
  // chunked selective scan + gating
  scan_part_k<<<BB * NCH * (DI / 64), 64, 0, stream>>>(delta, xdbl, A_log, prodA, hend);
  scan_comb_k<<<SEQS / 64, 64, 0, stream>>>(prodA, hend, hstart);
  scan_fin_k<<<BB * NCH * (DI / 64), 64, 0, stream>>>(delta, xdbl, A_log, Dp, xc, z,
                                                      hstart, ypbf);
  // out = y @ W_out.T (4096 x 768, K=1536), BM=64 -> 384 blocks (was 192)
  {
    dim3 g(768 / 128, 4096 / 64);
    gemm_pipe<0, 64><<<g, 256, 0, stream>>>(ypbf, Woutbf, out, nullptr, nullptr, MM, DM, DI);
  }
}

// Round 5
// 359.373 us; speedup vs baseline: 1.4442x; 1.4442x over previous
//
#include <hip/hip_runtime.h>
#include <hip/hip_bf16.h>

// Problem constants (B=2, L=2048, Dm=768, di=1536, ds=16, dc=4)
#define BB 2
#define LL 2048
#define DM 768
#define DI 1536
#define DS 16
#define MM (BB*LL)   // 4096 rows
#define NCH 32       // scan chunks
#define CHL 64       // steps per chunk
#define SEQS (BB*DI*DS)  // 49152 independent scalar recurrences
#define NC2 1664     // delta GEMM fused N: 1536 (W_dt) + 32 (W_x) + 96 pad = 13*128

typedef __hip_bfloat16 bf16;
typedef short bf16x8 __attribute__((ext_vector_type(8)));
typedef float f32x4  __attribute__((ext_vector_type(4)));

__device__ __forceinline__ void gl_lds16(const void* g, void* l) {
  __builtin_amdgcn_global_load_lds((const __attribute__((address_space(1))) void*)g,
                                   (__attribute__((address_space(3))) void*)l, 16, 0, 0);
}

// ---------------- fp32 -> bf16 convert (4 elems/thread) ----------------
struct bf4 { __hip_bfloat16 a, b, c, d; };
__global__ void cvt4_k(const float* __restrict__ in, __hip_bfloat16* __restrict__ out, int n4) {
  int i = blockIdx.x * 256 + threadIdx.x;
  if (i < n4) {
    float4 v = ((const float4*)in)[i];
    bf4 o = { __float2bfloat16(v.x), __float2bfloat16(v.y),
              __float2bfloat16(v.z), __float2bfloat16(v.w) };
    ((bf4*)out)[i] = o;
  }
}

// ---------------- build Wcomb[1664][1536] bf16 = [W_dt ; W_x ; 0-pad] ----------------
__global__ void wcomb_k(const float* __restrict__ Wdt, const float* __restrict__ Wx,
                        __hip_bfloat16* __restrict__ out) {
  int i = blockIdx.x * 256 + threadIdx.x;          // one float4 per thread
  if (i >= NC2 * DI / 4) return;
  int e = i * 4;
  int row = e / DI, colb = e % DI;
  float4 v;
  if (row < DI)            v = ((const float4*)Wdt)[i];
  else if (row < DI + 32)  v = *(const float4*)(Wx + (size_t)(row - DI) * DI + colb);
  else                     v = make_float4(0.f, 0.f, 0.f, 0.f);
  bf4 o = { __float2bfloat16(v.x), __float2bfloat16(v.y),
            __float2bfloat16(v.z), __float2bfloat16(v.w) };
  ((bf4*)out)[i] = o;
}

// ---------------- pipelined NT bf16 MFMA GEMM, BMx128 tile ----------------
// C[M,N] = A[M,K] * W[N,K]^T. 256 threads = 4 waves (2x2), wave tile (BM/2)x64.
// Staging: global_load_lds width=16 (no VGPR transit -> no spill risk).
// 3 LDS buffers, 2 tiles in flight. ONE barrier/iter: s_waitcnt vmcnt(NPW)
// (leaves next tile's loads in flight) + s_barrier. Loads for tile i+2 are
// issued AFTER barrier i, so tile i's loads get ~2 MFMA phases of latency cover.
// Safety: a wave reaches barrier i only after lgkm-draining its ds_reads of
// buf p(i-1) (value deps into MFMA), which is the buffer tile i+2 overwrites.
// EPI: 0 = plain fp32 store (stride N)
//      2 = split: col<DI -> C (stride DI), else -> C2 (stride DI)   [xz GEMM]
//      3 = col<DI -> softplus(v+bias[col]) -> C (stride DI);
//          col in [DI,DI+32) -> C2 (stride 32); else discard        [delta+xdbl]
template<int EPI, int BM>
__global__ __launch_bounds__(256) void gemm_db(const bf16* __restrict__ A,
                                               const bf16* __restrict__ W,
                                               float* __restrict__ C,
                                               float* __restrict__ C2,
                                               const float* __restrict__ bias,
                                               int M, int N, int K) {
  constexpr int NA  = BM / 64;        // gl_lds per wave for A tile
  constexpr int NPW = NA + 2;         // gl_lds per wave per tile (A + B)
  __shared__ short sA[3][BM * 32];
  __shared__ short sB[3][128 * 32];
  const int t = threadIdx.x;
  const int m0 = blockIdx.y * BM, n0 = blockIdx.x * 128;
  const int w = t >> 6, lane = t & 63;
  const int wm = (w >> 1) * (BM / 2), wn = (w & 1) * 64;
  const int ga = wm >> 4, gb = wn >> 4;

  f32x4 acc[BM / 32][4] = {};

  // wave w stages A row-blocks {w+4j, j<NA} and B row-blocks {w, w+4};
  // dest = wave-uniform base, lane-linear (frag idx == lane).
  const int srow = lane & 15, skoff = (lane >> 4) * 8;
  const bf16* gA[NA]; const bf16* gB[2];
  #pragma unroll
  for (int j = 0; j < NA; j++)
    gA[j] = A + (size_t)(m0 + (w + 4 * j) * 16 + srow) * K + skoff;
  #pragma unroll
  for (int j = 0; j < 2; j++)
    gB[j] = W + (size_t)(n0 + (w + 4 * j) * 16 + srow) * K + skoff;

  #define ISSUE(buf, k0)                                              \
    do {                                                              \
      _Pragma("unroll")                                               \
      for (int j = 0; j < NA; j++)                                    \
        gl_lds16(gA[j] + (k0), &sA[buf][(w + 4 * j) * 512]);          \
      _Pragma("unroll")                                               \
      for (int j = 0; j < 2; j++)                                     \
        gl_lds16(gB[j] + (k0), &sB[buf][(w + 4 * j) * 512]);          \
    } while (0)

  ISSUE(0, 0);
  ISSUE(1, 32);
  int p = 0;
  for (int k0 = 0; k0 < K; k0 += 32) {
    if (k0 + 32 < K) {
      asm volatile("s_waitcnt vmcnt(%0)\n\ts_barrier" :: "n"(NPW) : "memory");
    } else {
      asm volatile("s_waitcnt vmcnt(0)\n\ts_barrier" ::: "memory");
    }
    if (k0 + 64 < K) {
      int nb = p + 2; if (nb >= 3) nb -= 3;
      ISSUE(nb, k0 + 64);
    }
    const bf16x8* fA = (const bf16x8*)sA[p];
    const bf16x8* fB = (const bf16x8*)sB[p];
    bf16x8 af[BM / 32], bfr[4];
    #pragma unroll
    for (int i = 0; i < BM / 32; i++) af[i]  = fA[(ga + i) * 64 + lane];
    #pragma unroll
    for (int j = 0; j < 4; j++)       bfr[j] = fB[(gb + j) * 64 + lane];
    #pragma unroll
    for (int i = 0; i < BM / 32; i++)
      #pragma unroll
      for (int j = 0; j < 4; j++)
        acc[i][j] = __builtin_amdgcn_mfma_f32_16x16x32_bf16(af[i], bfr[j], acc[i][j], 0, 0, 0);
    p++; if (p >= 3) p = 0;
  }
  #undef ISSUE

  const int q = lane >> 4, mm = lane & 15;
  #pragma unroll
  for (int i = 0; i < BM / 32; i++)
    #pragma unroll
    for (int j = 0; j < 4; j++) {
      int r0  = m0 + wm + i * 16 + q * 4;
      int col = n0 + wn + j * 16 + mm;
      #pragma unroll
      for (int r = 0; r < 4; r++) {
        float v = acc[i][j][r];
        if (EPI == 0) {
          C[(size_t)(r0 + r) * N + col] = v;
        } else if (EPI == 2) {
          if (col < DI) C [(size_t)(r0 + r) * DI + col]        = v;
          else          C2[(size_t)(r0 + r) * DI + (col - DI)] = v;
        } else {  // EPI == 3
          if (col < DI) {
            float vv = v + bias[col];
            vv = (vv > 15.f) ? vv : __logf(1.f + __expf(vv));
            C[(size_t)(r0 + r) * DI + col] = vv;
          } else if (col < DI + 32) {
            C2[(size_t)(r0 + r) * 32 + (col - DI)] = v;
          }
        }
      }
    }
}

// ---------------- depthwise causal conv (dc=4) + SiLU; writes fp32 + bf16 ----------------
__global__ __launch_bounds__(256) void conv_silu_k(const float* __restrict__ xpart,
                                                   const float* __restrict__ Wc,
                                                   float* __restrict__ xc,
                                                   __hip_bfloat16* __restrict__ xcbf) {
  int idx = blockIdx.x * 256 + threadIdx.x;
  if (idx >= MM * DI) return;
  int d = idx % DI;
  int r = idx / DI;
  int l = r & (LL - 1);
  float4 wv = ((const float4*)Wc)[d];  // W_conv[d, 0, 0..3]
  const float* xp = xpart + (size_t)r * DI + d;
  float acc = wv.w * xp[0];
  if (l >= 1) acc += wv.z * xp[-(ptrdiff_t)DI];
  if (l >= 2) acc += wv.y * xp[-(ptrdiff_t)(2 * DI)];
  if (l >= 3) acc += wv.x * xp[-(ptrdiff_t)(3 * DI)];
  float s = acc / (1.f + __expf(-acc));   // silu
  xc[idx] = s;
  xcbf[idx] = __float2bfloat16(s);
}

// ================= chunked selective scan =================
__global__ __launch_bounds__(64) void scan_part_k(const float* __restrict__ delta,
                                                  const float* __restrict__ xdbl,
                                                  const float* __restrict__ A_log,
                                                  float* __restrict__ prodA,
                                                  float* __restrict__ hend) {
  __shared__ float sBC[CHL * 32];
  const int t = threadIdx.x;
  const int dg = blockIdx.x % (DI / 64);
  const int chunk = (blockIdx.x / (DI / 64)) % NCH;
  const int b = blockIdx.x / ((DI / 64) * NCH);
  const int d = dg * 64 + t;

  float a[16];
  #pragma unroll
  for (int s = 0; s < 16; s++) a[s] = -__expf(A_log[s]);

  const float4* src = (const float4*)(xdbl + ((size_t)b * LL + chunk * CHL) * 32);
  #pragma unroll
  for (int k = 0; k < 8; k++) ((float4*)sBC)[t + k * 64] = src[t + k * 64];
  __syncthreads();

  float h[16], p[16];
  #pragma unroll
  for (int s = 0; s < 16; s++) { h[s] = 0.f; p[s] = 1.f; }

  const float* dptr = delta + ((size_t)b * LL + chunk * CHL) * DI + d;
  #pragma unroll 2
  for (int i = 0; i < CHL; i++) {
    float dlt = dptr[(size_t)i * DI];
    const float4* bc = (const float4*)(sBC + i * 32);
    float4 B0 = bc[0], B1 = bc[1], B2 = bc[2], B3 = bc[3];
    float Bv[16] = {B0.x,B0.y,B0.z,B0.w, B1.x,B1.y,B1.z,B1.w,
                    B2.x,B2.y,B2.z,B2.w, B3.x,B3.y,B3.z,B3.w};
    #pragma unroll
    for (int s = 0; s < 16; s++) {
      float dA = __expf(dlt * a[s]);
      h[s] = dA * h[s] + dlt * Bv[s];
      p[s] *= dA;
    }
  }
  size_t o = (size_t)chunk * SEQS + ((size_t)b * DI + d) * 16;
  #pragma unroll
  for (int s = 0; s < 16; s += 4) {
    ((float4*)(prodA + o))[s >> 2] = make_float4(p[s], p[s+1], p[s+2], p[s+3]);
    ((float4*)(hend  + o))[s >> 2] = make_float4(h[s], h[s+1], h[s+2], h[s+3]);
  }
}

__global__ __launch_bounds__(64) void scan_comb_k(const float* __restrict__ prodA,
                                                  const float* __restrict__ hend,
                                                  float* __restrict__ hstart) {
  int idx = blockIdx.x * 64 + threadIdx.x;   // 0 .. SEQS-1
  float run = 0.f;
  #pragma unroll
  for (int c = 0; c < NCH; c++) {
    size_t o = (size_t)c * SEQS + idx;
    hstart[o] = run;
    run = prodA[o] * run + hend[o];
  }
}

__global__ __launch_bounds__(64) void scan_fin_k(const float* __restrict__ delta,
                                                 const float* __restrict__ xdbl,
                                                 const float* __restrict__ A_log,
                                                 const float* __restrict__ Dp,
                                                 const float* __restrict__ xc,
                                                 const float* __restrict__ z,
                                                 const float* __restrict__ hstart,
                                                 __hip_bfloat16* __restrict__ ypbf) {
  __shared__ float sBC[CHL * 32];
  const int t = threadIdx.x;
  const int dg = blockIdx.x % (DI / 64);
  const int chunk = (blockIdx.x / (DI / 64)) % NCH;
  const int b = blockIdx.x / ((DI / 64) * NCH);
  const int d = dg * 64 + t;

  float a[16];
  #pragma unroll
  for (int s = 0; s < 16; s++) a[s] = -__expf(A_log[s]);

  const float4* src = (const float4*)(xdbl + ((size_t)b * LL + chunk * CHL) * 32);
  #pragma unroll
  for (int k = 0; k < 8; k++) ((float4*)sBC)[t + k * 64] = src[t + k * 64];
  __syncthreads();

  float h[16];
  size_t o = (size_t)chunk * SEQS + ((size_t)b * DI + d) * 16;
  #pragma unroll
  for (int s = 0; s < 16; s += 4) {
    float4 v = ((const float4*)(hstart + o))[s >> 2];
    h[s] = v.x; h[s+1] = v.y; h[s+2] = v.z; h[s+3] = v.w;
  }
  const float Dv = Dp[d];

  const size_t rbase = (size_t)b * LL + chunk * CHL;
  const float* dptr = delta + rbase * DI + d;
  const float* xcp  = xc    + rbase * DI + d;
  const float* zp   = z     + rbase * DI + d;
  __hip_bfloat16* yp = ypbf + rbase * DI + d;

  #pragma unroll 2
  for (int i = 0; i < CHL; i++) {
    float dlt = dptr[(size_t)i * DI];
    const float4* bc = (const float4*)(sBC + i * 32);
    float4 B0 = bc[0], B1 = bc[1], B2 = bc[2], B3 = bc[3];
    float4 C0 = bc[4], C1 = bc[5], C2 = bc[6], C3 = bc[7];
    float Bv[16] = {B0.x,B0.y,B0.z,B0.w, B1.x,B1.y,B1.z,B1.w,
                    B2.x,B2.y,B2.z,B2.w, B3.x,B3.y,B3.z,B3.w};
    float Cv[16] = {C0.x,C0.y,C0.z,C0.w, C1.x,C1.y,C1.z,C1.w,
                    C2.x,C2.y,C2.z,C2.w, C3.x,C3.y,C3.z,C3.w};
    float y = 0.f;
    #pragma unroll
    for (int s = 0; s < 16; s++) {
      float dA = __expf(dlt * a[s]);
      h[s] = dA * h[s] + dlt * Bv[s];
      y += h[s] * Cv[s];
    }
    float xcv = xcp[(size_t)i * DI];
    float zv  = zp [(size_t)i * DI];
    float val = (y + Dv * xcv) * (zv / (1.f + __expf(-zv)));
    yp[(size_t)i * DI] = __float2bfloat16(val);
  }
}

extern "C" void kernel_launch(void* const* d_in, const int* in_sizes, int n_in,
                              void* d_out, int out_size, void* d_ws, size_t ws_size,
                              hipStream_t stream) {
  const float* x      = (const float*)d_in[0];
  const float* W_in   = (const float*)d_in[1];
  const float* W_conv = (const float*)d_in[2];
  const float* W_x    = (const float*)d_in[3];
  const float* W_dt   = (const float*)d_in[4];
  const float* b_dt   = (const float*)d_in[5];
  const float* A_log  = (const float*)d_in[6];
  const float* Dp     = (const float*)d_in[7];
  const float* W_out  = (const float*)d_in[8];
  float* out = (float*)d_out;

  char* ws = (char*)d_ws;
  // workspace layout (bytes), total 144441344
  float*          xpart  = (float*)(ws + 0);                         // 25165824
  float*          z      = (float*)(ws + 25165824);                  // 25165824
  __hip_bfloat16* xbf    = (__hip_bfloat16*)(ws + 50331648);         // 6291456 (dead after GEMM1)
  __hip_bfloat16* Winbf  = (__hip_bfloat16*)(ws + 56623104);         // 4718592
  float*          xc     = (float*)(ws + 61341696);                  // 25165824
  __hip_bfloat16* xcbf   = (__hip_bfloat16*)(ws + 86507520);         // 12582912
  float*          delta  = (float*)(ws + 103809024);                 // 25165824
  float*          xdbl   = (float*)(ws + 128974848);                 // 524288
  __hip_bfloat16* ypbf   = (__hip_bfloat16*)(ws + 129499136);        // 12582912
  __hip_bfloat16* Woutbf = (__hip_bfloat16*)(ws + 142082048);        // 2359296
  // aliases of dead regions:
  float*          prodA  = (float*)(ws + 0);                         // xpart region (dead after conv)
  float*          hend   = (float*)(ws + 6291456);
  float*          hstart = (float*)(ws + 12582912);
  __hip_bfloat16* Wcomb  = (__hip_bfloat16*)(ws + 50331648);         // xbf region: 1664*1536*2 = 5111808

  // fp32 -> bf16 converts
  cvt4_k<<<(786432 + 255) / 256, 256, 0, stream>>>(x, xbf, 786432);
  cvt4_k<<<(589824 + 255) / 256, 256, 0, stream>>>(W_in, Winbf, 589824);
  cvt4_k<<<(294912 + 255) / 256, 256, 0, stream>>>(W_out, Woutbf, 294912);

  // xz = x @ W_in.T (4096 x 3072, K=768), split-stored into xpart | z
  {
    dim3 g(3072 / 128, 4096 / 128);   // 768 blocks
    gemm_db<2, 128><<<g, 256, 0, stream>>>(xbf, Winbf, xpart, z, nullptr, MM, 2 * DI, DM);
  }
  // xc = silu(causal_dwconv(xpart))
  conv_silu_k<<<(MM * DI + 255) / 256, 256, 0, stream>>>(xpart, W_conv, xc, xcbf);
  // Wcomb = [W_dt ; W_x ; 0] bf16 (aliases xbf, dead after GEMM1)
  wcomb_k<<<(NC2 * DI / 4 + 255) / 256, 256, 0, stream>>>(W_dt, W_x, Wcomb);
  // delta = softplus(xc @ W_dt.T + b_dt) AND xdbl = xc @ W_x.T, one GEMM (N=1664)
  {
    dim3 g(NC2 / 128, 4096 / 128);    // 416 blocks
    gemm_db<3, 128><<<g, 256, 0, stream>>>(xcbf, Wcomb, delta, xdbl, b_dt, MM, NC2, DI);
  }
  // chunked selective scan + gating
  scan_part_k<<<BB * NCH * (DI / 64), 64, 0, stream>>>(delta, xdbl, A_log, prodA, hend);
  scan_comb_k<<<SEQS / 64, 64, 0, stream>>>(prodA, hend, hstart);
  scan_fin_k<<<BB * NCH * (DI / 64), 64, 0, stream>>>(delta, xdbl, A_log, Dp, xc, z,
                                                      hstart, ypbf);
  // out = y @ W_out.T (4096 x 768, K=1536), BM=64 -> 384 blocks
  {
    dim3 g(768 / 128, 4096 / 64);
    gemm_db<0, 64><<<g, 256, 0, stream>>>(ypbf, Woutbf, out, nullptr, nullptr, MM, DM, DI);
  }
}